// Round 10
// baseline (30600.748 us; speedup 1.0000x reference)
//
#include <hip/hip_runtime.h>

#define T_STEPS 512
#define BB 64
#define EE 300
#define EP 320
#define HH 512
#define G3 1536
#define HB (BB*HH)   // halves per h slot
#define RING 4

typedef _Float16 f16x8 __attribute__((ext_vector_type(8)));
typedef float f32x4 __attribute__((ext_vector_type(4)));
typedef int i32x4 __attribute__((ext_vector_type(4)));

#define MEMBAR() asm volatile("" ::: "memory")

__device__ __forceinline__ f32x4 mf(f16x8 a, f16x8 b, f32x4 c) {
  return __builtin_amdgcn_mfma_f32_16x16x32_f16(a, b, c, 0, 0, 0);
}

struct HMat { i32x4 q[16]; };   // 64 VGPRs: one lane's 16 fragments of a 64x512 f16 matrix

// 16 back-to-back MALL (sc1) 16B loads + FULL drain in ONE asm block
// (in-flight regs never escape a block — round-4 lesson). Proven h-data path.
#define LOADS16_MALL                                                 \
    "global_load_dwordx4 %0,  %16, %17 sc1\n\t"                      \
    "global_load_dwordx4 %1,  %16, %17 offset:64 sc1\n\t"            \
    "global_load_dwordx4 %2,  %16, %17 offset:128 sc1\n\t"           \
    "global_load_dwordx4 %3,  %16, %17 offset:192 sc1\n\t"           \
    "global_load_dwordx4 %4,  %16, %17 offset:256 sc1\n\t"           \
    "global_load_dwordx4 %5,  %16, %17 offset:320 sc1\n\t"           \
    "global_load_dwordx4 %6,  %16, %17 offset:384 sc1\n\t"           \
    "global_load_dwordx4 %7,  %16, %17 offset:448 sc1\n\t"           \
    "global_load_dwordx4 %8,  %16, %17 offset:512 sc1\n\t"           \
    "global_load_dwordx4 %9,  %16, %17 offset:576 sc1\n\t"           \
    "global_load_dwordx4 %10, %16, %17 offset:640 sc1\n\t"           \
    "global_load_dwordx4 %11, %16, %17 offset:704 sc1\n\t"           \
    "global_load_dwordx4 %12, %16, %17 offset:768 sc1\n\t"           \
    "global_load_dwordx4 %13, %16, %17 offset:832 sc1\n\t"           \
    "global_load_dwordx4 %14, %16, %17 offset:896 sc1\n\t"           \
    "global_load_dwordx4 %15, %16, %17 offset:960 sc1\n\t"           \
    "s_waitcnt vmcnt(0)"

#define HM_OUTS(m) "=v"((m).q[0]), "=v"((m).q[1]), "=v"((m).q[2]), "=v"((m).q[3]),   \
                   "=v"((m).q[4]), "=v"((m).q[5]), "=v"((m).q[6]), "=v"((m).q[7]),   \
                   "=v"((m).q[8]), "=v"((m).q[9]), "=v"((m).q[10]), "=v"((m).q[11]), \
                   "=v"((m).q[12]), "=v"((m).q[13]), "=v"((m).q[14]), "=v"((m).q[15])

__device__ __forceinline__ void load16_mall(HMat& m, const void* base, int voff) {
  asm volatile(LOADS16_MALL : HM_OUTS(m) : "v"(voff), "s"(base) : "memory");
}

// batched x-prefetch: 10 plain cached loads + full drain (x0 is immutable)
__device__ __forceinline__ void loadx10_wait(i32x4* xq, const void* base, int voff) {
  asm volatile(
    "global_load_dwordx4 %0, %10, %11\n\t"
    "global_load_dwordx4 %1, %10, %11 offset:64\n\t"
    "global_load_dwordx4 %2, %10, %11 offset:128\n\t"
    "global_load_dwordx4 %3, %10, %11 offset:192\n\t"
    "global_load_dwordx4 %4, %10, %11 offset:256\n\t"
    "global_load_dwordx4 %5, %10, %11 offset:320\n\t"
    "global_load_dwordx4 %6, %10, %11 offset:384\n\t"
    "global_load_dwordx4 %7, %10, %11 offset:448\n\t"
    "global_load_dwordx4 %8, %10, %11 offset:512\n\t"
    "global_load_dwordx4 %9, %10, %11 offset:576\n\t"
    "s_waitcnt vmcnt(0)"
    : "=v"(xq[0]), "=v"(xq[1]), "=v"(xq[2]), "=v"(xq[3]), "=v"(xq[4]),
      "=v"(xq[5]), "=v"(xq[6]), "=v"(xq[7]), "=v"(xq[8]), "=v"(xq[9])
    : "v"(voff), "s"(base) : "memory");
}

__device__ __forceinline__ f16x8 fragq(i32x4 q) {
  union { i32x4 i; f16x8 v; } x; x.i = q; return x.v;
}

// h-tile publish to MALL (proven pair with sc1 loads)
__device__ __forceinline__ void st16_mall(void* p, f16x8 v) {
  i32x4 iv;
  __builtin_memcpy(&iv, &v, 16);
  asm volatile("global_store_dwordx4 %0, %1, off sc0 sc1" :: "v"(p), "v"(iv) : "memory");
}

// ---- L2-executed atomics: the same-XCD sync primitive. Atomic RMWs always
// bypass L1 and execute at the issuing XCD's L2 (TCC) — no allocation-policy
// surprises (r8: stale L1 hit; r9: sc0 stores never allocated in L2).
__device__ __forceinline__ void at_or_l2(int* p, int v) {
  asm volatile("global_atomic_or %0, %1, off" :: "v"(p), "v"(v) : "memory");
}
__device__ __forceinline__ void at_add_l2(int* p, int v) {
  asm volatile("global_atomic_add %0, %1, off" :: "v"(p), "v"(v) : "memory");
}
__device__ __forceinline__ int at_rd_l2(int* p) {   // atomic-or 0 = L2-executed read
  int r;
  asm volatile("global_atomic_or %0, %1, %2, off sc0\n\ts_waitcnt vmcnt(0)"
               : "=v"(r) : "v"(p), "v"(0) : "memory");
  return r;
}

// device-scope (MALL) plain ops for cross-XCD edges / fallback
__device__ __forceinline__ void st1_dev(char* p, int v) {
  asm volatile("global_store_byte %0, %1, off sc0 sc1" :: "v"(p), "v"(v) : "memory");
}
__device__ __forceinline__ void st4_dev(int* p, int v) {
  asm volatile("global_store_dword %0, %1, off sc0 sc1" :: "v"(p), "v"(v) : "memory");
}
__device__ __forceinline__ int ld4_dev(const int* p) {
  int r;
  asm volatile("global_load_dword %0, %1, off sc1\n\ts_waitcnt vmcnt(0)"
               : "=v"(r) : "v"(p) : "memory");
  return r;
}

// WG wait: only wave 0 polls, then __syncthreads releases the rest.
// Lanes 0-31: intra-layer edge via L2 atomics (dev copy OR-ed in every 8th
// iter — flags are monotone 0->1, OR is safe). Lanes 32-63: cross-layer edge
// via device-scope loads (those edges carry slack).
__device__ __forceinline__ void wg_wait(int* aL2, const int* aDev, const int* bDev) {
  if ((threadIdx.x >> 6) == 0) {
    const int lane = threadIdx.x & 63;
    int* pa2 = nullptr; const int* pad = nullptr; const int* pbd = nullptr;
    if (lane < 32) { if (aDev) { pa2 = aL2 ? (aL2 + lane) : nullptr; pad = aDev + lane; } }
    else           { if (bDev) pbd = bDev + (lane - 32); }
    int it = 0;
    for (;;) {
      int ok = 1;
      if (pad) {
        int v = pa2 ? at_rd_l2(pa2) : ld4_dev(pad);
        if (pa2 && ((it & 7) == 7)) v |= ld4_dev(pad);
        ok = (v == 0x01010101);
      } else if (pbd) {
        ok = (ld4_dev(pbd) == 0x01010101);
      }
      if (__all(ok)) break;
      ++it;
    }
  }
  __syncthreads();
}

__device__ __forceinline__ float sigf(float x) { return 1.f / (1.f + __expf(-x)); }

struct B3 { f16x8 r, z, n; };
__device__ __forceinline__ B3 ldB(const _Float16* __restrict__ W, int K, int row0, int koff) {
  B3 o;
  const _Float16* p = W + (size_t)row0 * K + koff;
  o.r = *(const f16x8*)p;
  o.z = *(const f16x8*)(p + (size_t)512 * K);
  o.n = *(const f16x8*)(p + (size_t)1024 * K);
  return o;
}

__global__ void prep_x0(const int* __restrict__ texts, const float* __restrict__ emb,
                        _Float16* __restrict__ x0) {
  const size_t N = (size_t)T_STEPS * BB * EP;
  const size_t stride = (size_t)gridDim.x * blockDim.x;
  for (size_t i = (size_t)blockIdx.x * blockDim.x + threadIdx.x; i < N; i += stride) {
    int e = (int)(i % EP);
    size_t tb = i / EP;
    float v = 0.f;
    if (e < EE) v = emb[(size_t)texts[tb] * EE + e];
    x0[i] = (_Float16)v;
  }
}

__global__ void prep_w(const float* __restrict__ Wih0, const float* __restrict__ Whh0,
                       const float* __restrict__ bih0, const float* __restrict__ bhh0,
                       const float* __restrict__ Wih1, const float* __restrict__ Whh1,
                       const float* __restrict__ bih1, const float* __restrict__ bhh1,
                       _Float16* __restrict__ W0x, _Float16* __restrict__ W0h,
                       _Float16* __restrict__ W1x, _Float16* __restrict__ W1h,
                       float* __restrict__ bias0, float* __restrict__ bias1) {
  const size_t stride = (size_t)gridDim.x * blockDim.x;
  const size_t gid = (size_t)blockIdx.x * blockDim.x + threadIdx.x;
  for (size_t i = gid; i < (size_t)G3 * EP; i += stride) {
    int k = (int)(i % EP); int n = (int)(i / EP);
    W0x[i] = (k < EE) ? (_Float16)Wih0[(size_t)n * EE + k] : (_Float16)0.f;
  }
  for (size_t i = gid; i < (size_t)G3 * HH; i += stride) {
    W0h[i] = (_Float16)Whh0[i];
    W1x[i] = (_Float16)Wih1[i];
    W1h[i] = (_Float16)Whh1[i];
  }
  for (size_t i = gid; i < (size_t)HH; i += stride) {
    bias0[i]        = bih0[i] + bhh0[i];
    bias0[512 + i]  = bih0[512 + i] + bhh0[512 + i];
    bias0[1024 + i] = bih0[1024 + i];
    bias0[1536 + i] = bhh0[1024 + i];
    bias1[i]        = bih1[i] + bhh1[i];
    bias1[512 + i]  = bih1[512 + i] + bhh1[512 + i];
    bias1[1024 + i] = bih1[1024 + i];
    bias1[1536 + i] = bhh1[1024 + i];
  }
}

// 768 launched WGs; 64 claim roles on TWO physical XCDs (first XCD to seat
// 32 WGs = layer 0, second = layer 1). Intra-layer per-step flags: L2 atomics
// (XCD-local). Cross-layer edges: device-scope flag copies. h data: MALL sc1.
__global__ __launch_bounds__(256, 1) void gru_persistent(
    const _Float16* __restrict__ x0,
    const _Float16* __restrict__ W0x, const _Float16* __restrict__ W0h,
    const _Float16* __restrict__ W1x, const _Float16* __restrict__ W1h,
    const float* __restrict__ bias0, const float* __restrict__ bias1,
    _Float16* h1ring, _Float16* h2buf, float* pooled,
    int* flags0L2, int* flags1L2, int* flags0d, int* flags1d,
    int* claim, int* winner)
{
  const int tid = threadIdx.x;
  __shared__ int s_role;
  __shared__ _Float16 tile[2][4][16][16];
  __shared__ float accum[T_STEPS][16];

  if (tid == 0) {
    int xcd;
    asm volatile("s_getreg_b32 %0, hwreg(HW_REG_XCC_ID)" : "=s"(xcd));
    xcd &= 7;
    int idx = __hip_atomic_fetch_add(claim + xcd * 16, 1, __ATOMIC_RELAXED,
                                     __HIP_MEMORY_SCOPE_AGENT);
    int role = -1;
    if (idx < 32) {
      if (idx == 31) {
        int exp = 0;
        if (!__hip_atomic_compare_exchange_strong(winner, &exp, xcd + 1,
              __ATOMIC_RELEASE, __ATOMIC_RELAXED, __HIP_MEMORY_SCOPE_AGENT)) {
          exp = 0;
          __hip_atomic_compare_exchange_strong(winner + 1, &exp, xcd + 1,
              __ATOMIC_RELEASE, __ATOMIC_RELAXED, __HIP_MEMORY_SCOPE_AGENT);
        }
      }
      int wa, wb;
      for (;;) {
        wa = __hip_atomic_load(winner,     __ATOMIC_RELAXED, __HIP_MEMORY_SCOPE_AGENT);
        wb = __hip_atomic_load(winner + 1, __ATOMIC_RELAXED, __HIP_MEMORY_SCOPE_AGENT);
        if (wa != 0 && wb != 0) break;
        __builtin_amdgcn_s_sleep(8);
      }
      if      (wa == xcd + 1) role = idx;
      else if (wb == xcd + 1) role = 32 + idx;
    }
    s_role = role;
  }
  __syncthreads();
  const int role = s_role;
  if (role < 0) return;

  const int L    = role >> 5;
  const int w    = role & 31;
  const int jb   = w * 16;
  const int bsub = tid >> 6;
  const int lane = tid & 63;
  const int quad = lane >> 4;
  const int l15  = lane & 15;
  const int brow = bsub * 16 + l15;
  const int j    = jb + l15;
  const int koff = quad * 8;
  const int hoff = brow * (HH * 2) + quad * 16;

  for (int i = tid; i < T_STEPS * 16; i += 256) ((float*)accum)[i] = 0.f;
  __syncthreads();

  if (L == 0) {
    const float br = bias0[j], bz = bias0[512 + j];
    const float bnx = bias0[1024 + j], bnh = bias0[1536 + j];
    const int xoff = brow * (EP * 2) + quad * 16;
    i32x4 xq[10];
    loadx10_wait(xq, x0, xoff);
    for (int s = 0; s < T_STEPS; ++s) {
      f32x4 aR = {0.f,0.f,0.f,0.f}, aZ = {0.f,0.f,0.f,0.f};
      f32x4 aNX = {0.f,0.f,0.f,0.f}, aNH = {0.f,0.f,0.f,0.f};
      #pragma unroll 5
      for (int c = 0; c < 10; ++c) {
        f16x8 a = fragq(xq[c]);
        B3 bb = ldB(W0x, EP, j, c * 32 + koff);
        aR = mf(a, bb.r, aR); aZ = mf(a, bb.z, aZ); aNX = mf(a, bb.n, aNX);
      }
      // intra edge: h1[s-1] published (L2 atomics); cross edge: ring slot free
      wg_wait((s >= 1)    ? flags0L2 + (size_t)(s - 1) * 32    : nullptr,
              (s >= 1)    ? flags0d  + (size_t)(s - 1) * 32    : nullptr,
              (s >= RING) ? flags1d  + (size_t)(s - RING) * 32 : nullptr);
      if (s >= 1) {
        HMat hA;
        load16_mall(hA, h1ring + ((s - 1) & (RING - 1)) * HB, hoff);
        #pragma unroll 4
        for (int c = 0; c < 16; ++c) {
          f16x8 a = fragq(hA.q[c]);
          B3 bb = ldB(W0h, HH, j, c * 32 + koff);
          aR = mf(a, bb.r, aR); aZ = mf(a, bb.z, aZ); aNH = mf(a, bb.n, aNH);
        }
      }

      _Float16 (*tc)[16] = tile[s & 1][bsub];
      _Float16 (*tp)[16] = tile[(s + 1) & 1][bsub];
      #pragma unroll
      for (int rg = 0; rg < 4; ++rg) {
        const int rr = quad * 4 + rg;
        float r = sigf(aR[rg] + br);
        float z = sigf(aZ[rg] + bz);
        float n = tanhf(aNX[rg] + bnx + r * (aNH[rg] + bnh));
        float hp = (s >= 1) ? (float)tp[rr][l15] : 0.f;
        tc[rr][l15] = (_Float16)((1.f - z) * n + z * hp);
      }
      if (lane < 32) {
        const int row = lane >> 1, seg = lane & 1;
        f16x8 v = *(const f16x8*)&tc[row][seg * 8];
        st16_mall(h1ring + (s & (RING - 1)) * HB + (size_t)(bsub * 16 + row) * HH + jb + seg * 8, v);
      }
      __builtin_amdgcn_s_waitcnt(0);            // h at MALL before flags
      if (lane == 0) {
        at_or_l2(flags0L2 + (size_t)s * 32 + w, 1 << (8 * bsub));
        st1_dev((char*)(flags0d + (size_t)s * 32 + w) + bsub, 1);
      }
      if (s + 1 < T_STEPS)
        loadx10_wait(xq, x0 + (size_t)(s + 1) * BB * EP, xoff);
    }
  } else {
    const float br = bias1[j], bz = bias1[512 + j];
    const float bnx = bias1[1024 + j], bnh = bias1[1536 + j];
    for (int t = 0; t < T_STEPS; ++t) {
      f32x4 aR = {0.f,0.f,0.f,0.f}, aZ = {0.f,0.f,0.f,0.f};
      f32x4 aNX = {0.f,0.f,0.f,0.f}, aNH = {0.f,0.f,0.f,0.f};
      // phase 1: self-recurrence edge (intra-XCD, critical) via L2 atomics
      wg_wait((t >= 1) ? flags1L2 + (size_t)(t - 1) * 32 : nullptr,
              (t >= 1) ? flags1d  + (size_t)(t - 1) * 32 : nullptr,
              nullptr);
      if (t >= 1) {
        HMat A2;
        load16_mall(A2, h2buf + ((t - 1) & 1) * HB, hoff);
        #pragma unroll 4
        for (int c = 0; c < 16; ++c) {
          f16x8 a = fragq(A2.q[c]);
          B3 bb = ldB(W1h, HH, j, c * 32 + koff);
          aR = mf(a, bb.r, aR); aZ = mf(a, bb.z, aZ); aNH = mf(a, bb.n, aNH);
        }
      }
      // phase 2: h1[t] from layer 0 (cross-XCD; L0 runs ahead -> slack)
      wg_wait(nullptr, flags0d + (size_t)t * 32, nullptr);
      {
        HMat A1;
        load16_mall(A1, h1ring + (t & (RING - 1)) * HB, hoff);
        #pragma unroll 4
        for (int c = 0; c < 16; ++c) {
          f16x8 a = fragq(A1.q[c]);
          B3 bb = ldB(W1x, HH, j, c * 32 + koff);
          aR = mf(a, bb.r, aR); aZ = mf(a, bb.z, aZ); aNX = mf(a, bb.n, aNX);
        }
      }

      _Float16 (*tc)[16] = tile[t & 1][bsub];
      _Float16 (*tp)[16] = tile[(t + 1) & 1][bsub];
      #pragma unroll
      for (int rg = 0; rg < 4; ++rg) {
        const int rr = quad * 4 + rg;
        float r = sigf(aR[rg] + br);
        float z = sigf(aZ[rg] + bz);
        float n = tanhf(aNX[rg] + bnx + r * (aNH[rg] + bnh));
        float hp = (t >= 1) ? (float)tp[rr][l15] : 0.f;
        tc[rr][l15] = (_Float16)((1.f - z) * n + z * hp);
      }
      if (lane < 32) {
        const int row = lane >> 1, seg = lane & 1;
        f16x8 v = *(const f16x8*)&tc[row][seg * 8];
        st16_mall(h2buf + (t & 1) * HB + (size_t)(bsub * 16 + row) * HH + jb + seg * 8, v);
      }
      __builtin_amdgcn_s_waitcnt(0);
      if (lane == 0) {
        at_or_l2(flags1L2 + (size_t)t * 32 + w, 1 << (8 * bsub));
        st1_dev((char*)(flags1d + (size_t)t * 32 + w) + bsub, 1);
      }
      if (lane < 16) {
        float sum = 0.f;
        #pragma unroll
        for (int r = 0; r < 16; ++r) sum += (float)tc[r][lane];
        atomicAdd(&accum[t][lane], sum);
      }
    }
    __syncthreads();
    for (int i = tid; i < T_STEPS * 16; i += 256) {
      int t = i >> 4, u = i & 15;
      pooled[(size_t)t * HH + jb + u] = accum[t][u];
    }
  }
}

__global__ void fc_kernel(const float* __restrict__ pooled, const float* __restrict__ fcW,
                          const float* __restrict__ fcb, float* __restrict__ out) {
  const int t = blockIdx.x;
  const int lane = threadIdx.x;
  float a0 = 0.f, a1 = 0.f, a2 = 0.f, a3 = 0.f, a4 = 0.f;
  for (int jj = lane; jj < HH; jj += 64) {
    float p = pooled[(size_t)t * HH + jj];
    a0 += p * fcW[jj];
    a1 += p * fcW[512 + jj];
    a2 += p * fcW[1024 + jj];
    a3 += p * fcW[1536 + jj];
    a4 += p * fcW[2048 + jj];
  }
  #pragma unroll
  for (int off = 32; off > 0; off >>= 1) {
    a0 += __shfl_down(a0, off, 64);
    a1 += __shfl_down(a1, off, 64);
    a2 += __shfl_down(a2, off, 64);
    a3 += __shfl_down(a3, off, 64);
    a4 += __shfl_down(a4, off, 64);
  }
  if (lane == 0) {
    const float sc = 1.f / 64.f;
    out[t * 5 + 0] = a0 * sc + fcb[0];
    out[t * 5 + 1] = a1 * sc + fcb[1];
    out[t * 5 + 2] = a2 * sc + fcb[2];
    out[t * 5 + 3] = a3 * sc + fcb[3];
    out[t * 5 + 4] = a4 * sc + fcb[4];
  }
}

// ---- PROBE A: device-scope (sc1/MALL) ping-pong between 2 WGs. ----
// dur_us / 512 = 2 x one-way hop (store visibility + poll RT).
__global__ void probe_sc1(int* buf) {
  if (threadIdx.x != 0) return;
  int* a = buf; int* b = buf + 32;
  if (blockIdx.x == 0) {
    for (int i = 1; i <= 512; ++i) { st4_dev(a, i); while (ld4_dev(b) < i) {} }
  } else {
    for (int i = 1; i <= 512; ++i) { while (ld4_dev(a) < i) {} st4_dev(b, i); }
  }
}

// ---- PROBE B: L2-atomic ping-pong between 2 WGs on the SAME XCD. ----
__global__ void probe_l2(int* buf, int* claim2, int* winner2) {
  __shared__ int s_role;
  if (threadIdx.x == 0) {
    int xcd; asm volatile("s_getreg_b32 %0, hwreg(HW_REG_XCC_ID)" : "=s"(xcd)); xcd &= 7;
    int idx = __hip_atomic_fetch_add(claim2 + xcd * 16, 1, __ATOMIC_RELAXED,
                                     __HIP_MEMORY_SCOPE_AGENT);
    int role = -1;
    if (idx < 2) {
      if (idx == 1) {
        int e = 0;
        __hip_atomic_compare_exchange_strong(winner2, &e, xcd + 1,
            __ATOMIC_RELEASE, __ATOMIC_RELAXED, __HIP_MEMORY_SCOPE_AGENT);
      }
      int wv;
      while ((wv = __hip_atomic_load(winner2, __ATOMIC_RELAXED,
                                     __HIP_MEMORY_SCOPE_AGENT)) == 0)
        __builtin_amdgcn_s_sleep(8);
      if (wv == xcd + 1) role = idx;
    }
    s_role = role;
  }
  __syncthreads();
  if (s_role < 0 || threadIdx.x != 0) return;
  int* a = buf; int* b = buf + 32;
  if (s_role == 0) {
    for (int i = 1; i <= 512; ++i) { at_add_l2(a, 1); while (at_rd_l2(b) < i) {} }
  } else {
    for (int i = 1; i <= 512; ++i) { while (at_rd_l2(a) < i) {} at_add_l2(b, 1); }
  }
}

// ---- PROBE C: one WG, 512 iterations of the L1 compute cell (96 MFMA +
// gates + real ldB weight traffic). dur_us / 512 = per-stage compute floor.
__global__ __launch_bounds__(256, 1) void probe_comp(
    const _Float16* __restrict__ W1x, const _Float16* __restrict__ W1h,
    float* sink) {
  const int tid = threadIdx.x, lane = tid & 63, quad = lane >> 4, l15 = lane & 15;
  const int j = l15, koff = quad * 8;
  HMat A1, A2;
  #pragma unroll
  for (int c = 0; c < 16; ++c) {
    i32x4 z = {0, 0, 0, 0};
    A1.q[c] = z; A2.q[c] = z;
  }
  f32x4 aT = {0.f, 0.f, 0.f, 0.f};
  for (int t = 0; t < 512; ++t) {
    MEMBAR();   // force weight reloads each iteration
    A1.q[0][0] += (__float_as_int(aT[0]) & 1);   // loop-carried dep: no hoisting
    f32x4 aR = {0.f,0.f,0.f,0.f}, aZ = {0.f,0.f,0.f,0.f};
    f32x4 aNX = {0.f,0.f,0.f,0.f}, aNH = {0.f,0.f,0.f,0.f};
    #pragma unroll 4
    for (int c = 0; c < 16; ++c) {
      f16x8 a = fragq(A1.q[c]);
      B3 bb = ldB(W1x, HH, j, c * 32 + koff);
      aR = mf(a, bb.r, aR); aZ = mf(a, bb.z, aZ); aNX = mf(a, bb.n, aNX);
    }
    #pragma unroll 4
    for (int c = 0; c < 16; ++c) {
      f16x8 a = fragq(A2.q[c]);
      B3 bb = ldB(W1h, HH, j, c * 32 + koff);
      aR = mf(a, bb.r, aR); aZ = mf(a, bb.z, aZ); aNH = mf(a, bb.n, aNH);
    }
    #pragma unroll
    for (int rg = 0; rg < 4; ++rg) {
      float r = sigf(aR[rg]);
      float z = sigf(aZ[rg]);
      float n = tanhf(aNX[rg] + r * aNH[rg]);
      aT[rg] = (1.f - z) * n + z * aT[rg];
    }
  }
  sink[tid] = aT[0] + aT[1] + aT[2] + aT[3];
}

extern "C" void kernel_launch(void* const* d_in, const int* in_sizes, int n_in,
                              void* d_out, int out_size, void* d_ws, size_t ws_size,
                              hipStream_t stream) {
  const int*   texts = (const int*)  d_in[0];
  const float* emb   = (const float*)d_in[1];
  const float* Wih0  = (const float*)d_in[2];
  const float* Whh0  = (const float*)d_in[3];
  const float* bih0  = (const float*)d_in[4];
  const float* bhh0  = (const float*)d_in[5];
  const float* Wih1  = (const float*)d_in[6];
  const float* Whh1  = (const float*)d_in[7];
  const float* bih1  = (const float*)d_in[8];
  const float* bhh1  = (const float*)d_in[9];
  const float* fcW   = (const float*)d_in[10];
  const float* fcb   = (const float*)d_in[11];
  float* out = (float*)d_out;

  char* ws = (char*)d_ws;
  int*      claim    = (int*)ws;                      // 8 XCD counters, 64B apart
  int*      winner   = (int*)(ws + 2048);             // [0]=layer0 XCD+1, [1]=layer1
  int*      flags0L2 = (int*)(ws + 4096);             // 65536 B [512][32] (L2 atomics)
  int*      flags1L2 = (int*)(ws + 69632);            // 65536 B
  int*      flags0d  = (int*)(ws + 135168);           // 65536 B (device copy)
  int*      flags1d  = (int*)(ws + 200704);           // 65536 B
  float*    pooled   = (float*)(ws + 266240);         // 1048576 B [512][512] f32
  _Float16* h1ring   = (_Float16*)(ws + 1314816);     // 262144 B (4 x 64x512 f16)
  _Float16* h2buf    = (_Float16*)(ws + 1576960);     // 131072 B (2 slots)
  _Float16* x0       = (_Float16*)(ws + 1708032);     // 20971520 B [512][64][320]
  _Float16* W0x      = (_Float16*)(ws + 22679552);    // 983040 B  [1536][320]
  _Float16* W0h      = (_Float16*)(ws + 23662592);    // 1572864 B [1536][512]
  _Float16* W1x      = (_Float16*)(ws + 25235456);    // 1572864 B
  _Float16* W1h      = (_Float16*)(ws + 26808320);    // 1572864 B
  float*    bias0    = (float*)(ws + 28381184);       // 8192 B
  float*    bias1    = (float*)(ws + 28389376);       // 8192 B
  int*      claim2   = (int*)(ws + 28397568);         // 2048 B (probe B claim)
  int*      winner2  = (int*)(ws + 28399616);         // 64 B
  int*      pbufA    = (int*)(ws + 28399680);         // 512 B (probe A)
  int*      pbufB    = (int*)(ws + 28400192);         // 512 B (probe B)
  float*    sink     = (float*)(ws + 28400704);       // 1024 B (probe C)
  // total ws use: 28401728 B

  hipMemsetAsync(ws, 0, 266240, stream);              // claim/winner/flags
  hipMemsetAsync(ws + 28397568, 0, 3136, stream);     // probe claim/buffers
  prep_x0<<<4096, 256, 0, stream>>>(texts, emb, x0);
  prep_w<<<1024, 256, 0, stream>>>(Wih0, Whh0, bih0, bhh0, Wih1, Whh1, bih1, bhh1,
                                   W0x, W0h, W1x, W1h, bias0, bias1);
  gru_persistent<<<768, 256, 0, stream>>>(x0, W0x, W0h, W1x, W1h, bias0, bias1,
                                          h1ring, h2buf, pooled,
                                          flags0L2, flags1L2, flags0d, flags1d,
                                          claim, winner);
  fc_kernel<<<512, 64, 0, stream>>>(pooled, fcW, fcb, out);
  probe_sc1<<<2, 64, 0, stream>>>(pbufA);
  probe_l2<<<64, 64, 0, stream>>>(pbufB, claim2, winner2);
  probe_comp<<<1, 256, 0, stream>>>(W1x, W1h, sink);
}

// Round 11
// 9473.820 us; speedup vs baseline: 3.2300x; 3.2300x over previous
//
#include <hip/hip_runtime.h>

#define T_STEPS 512
#define BB 64
#define EE 300
#define EP 320
#define HH 512
#define HB (BB*HH)   // halves per h slot
#define RING 4
#define NCOL 8       // output columns per WG
#define NWG 64       // WGs per layer

typedef _Float16 f16x8 __attribute__((ext_vector_type(8)));
typedef float f32x4 __attribute__((ext_vector_type(4)));
typedef int i32x4 __attribute__((ext_vector_type(4)));

__device__ __forceinline__ f32x4 mf(f16x8 a, f16x8 b, f32x4 c) {
  return __builtin_amdgcn_mfma_f32_16x16x32_f16(a, b, c, 0, 0, 0);
}

struct HMat { i32x4 q[16]; };   // 64 VGPRs: one lane's 16 A-fragments of a 64x512 f16 matrix

// 16 back-to-back MALL (sc1) 16B loads + FULL drain in ONE asm block
// (in-flight regs never escape a block — round-4 lesson). Proven h-data path.
#define LOADS16_MALL                                                 \
    "global_load_dwordx4 %0,  %16, %17 sc1\n\t"                      \
    "global_load_dwordx4 %1,  %16, %17 offset:64 sc1\n\t"            \
    "global_load_dwordx4 %2,  %16, %17 offset:128 sc1\n\t"           \
    "global_load_dwordx4 %3,  %16, %17 offset:192 sc1\n\t"           \
    "global_load_dwordx4 %4,  %16, %17 offset:256 sc1\n\t"           \
    "global_load_dwordx4 %5,  %16, %17 offset:320 sc1\n\t"           \
    "global_load_dwordx4 %6,  %16, %17 offset:384 sc1\n\t"           \
    "global_load_dwordx4 %7,  %16, %17 offset:448 sc1\n\t"           \
    "global_load_dwordx4 %8,  %16, %17 offset:512 sc1\n\t"           \
    "global_load_dwordx4 %9,  %16, %17 offset:576 sc1\n\t"           \
    "global_load_dwordx4 %10, %16, %17 offset:640 sc1\n\t"           \
    "global_load_dwordx4 %11, %16, %17 offset:704 sc1\n\t"           \
    "global_load_dwordx4 %12, %16, %17 offset:768 sc1\n\t"           \
    "global_load_dwordx4 %13, %16, %17 offset:832 sc1\n\t"           \
    "global_load_dwordx4 %14, %16, %17 offset:896 sc1\n\t"           \
    "global_load_dwordx4 %15, %16, %17 offset:960 sc1\n\t"           \
    "s_waitcnt vmcnt(0)"

#define HM_OUTS(m) "=v"((m).q[0]), "=v"((m).q[1]), "=v"((m).q[2]), "=v"((m).q[3]),   \
                   "=v"((m).q[4]), "=v"((m).q[5]), "=v"((m).q[6]), "=v"((m).q[7]),   \
                   "=v"((m).q[8]), "=v"((m).q[9]), "=v"((m).q[10]), "=v"((m).q[11]), \
                   "=v"((m).q[12]), "=v"((m).q[13]), "=v"((m).q[14]), "=v"((m).q[15])

__device__ __forceinline__ void load16_mall(HMat& m, const void* base, int voff) {
  asm volatile(LOADS16_MALL : HM_OUTS(m) : "v"(voff), "s"(base) : "memory");
}

// batched x-prefetch: 10 plain cached loads + full drain (x0 is immutable)
__device__ __forceinline__ void loadx10_wait(i32x4* xq, const void* base, int voff) {
  asm volatile(
    "global_load_dwordx4 %0, %10, %11\n\t"
    "global_load_dwordx4 %1, %10, %11 offset:64\n\t"
    "global_load_dwordx4 %2, %10, %11 offset:128\n\t"
    "global_load_dwordx4 %3, %10, %11 offset:192\n\t"
    "global_load_dwordx4 %4, %10, %11 offset:256\n\t"
    "global_load_dwordx4 %5, %10, %11 offset:320\n\t"
    "global_load_dwordx4 %6, %10, %11 offset:384\n\t"
    "global_load_dwordx4 %7, %10, %11 offset:448\n\t"
    "global_load_dwordx4 %8, %10, %11 offset:512\n\t"
    "global_load_dwordx4 %9, %10, %11 offset:576\n\t"
    "s_waitcnt vmcnt(0)"
    : "=v"(xq[0]), "=v"(xq[1]), "=v"(xq[2]), "=v"(xq[3]), "=v"(xq[4]),
      "=v"(xq[5]), "=v"(xq[6]), "=v"(xq[7]), "=v"(xq[8]), "=v"(xq[9])
    : "v"(voff), "s"(base) : "memory");
}

__device__ __forceinline__ f16x8 fragq(i32x4 q) {
  union { i32x4 i; f16x8 v; } x; x.i = q; return x.v;
}

// h-tile publish to MALL (proven pair with sc1 loads)
__device__ __forceinline__ void st16_mall(void* p, f16x8 v) {
  i32x4 iv;
  __builtin_memcpy(&iv, &v, 16);
  asm volatile("global_store_dwordx4 %0, %1, off sc0 sc1" :: "v"(p), "v"(iv) : "memory");
}

// device-scope flag publish / poll (proven r5 pair)
__device__ __forceinline__ void st1_dev(char* p, int v) {
  asm volatile("global_store_byte %0, %1, off sc0 sc1" :: "v"(p), "v"(v) : "memory");
}
__device__ __forceinline__ int ld4_dev(const int* p) {
  int r;
  asm volatile("global_load_dword %0, %1, off sc1\n\ts_waitcnt vmcnt(0)"
               : "=v"(r) : "v"(p) : "memory");
  return r;
}

// WG wait: wave 0 polls edge A (64 producer words), wave 1 edge B; waves 2-3
// go straight to the barrier. Flag word = 4 bytes = the 4 waves of one producer WG.
__device__ __forceinline__ void wg_wait2(const int* fA, const int* fB) {
  const int wv = threadIdx.x >> 6, lane = threadIdx.x & 63;
  const int* p = (wv == 0) ? fA : (wv == 1 ? fB : nullptr);
  if (p) {
    const int* q = p + lane;
    while (!__all(ld4_dev(q) == 0x01010101)) {}
  }
  __syncthreads();
}

__device__ __forceinline__ float sigf(float x) { return 1.f / (1.f + __expf(-x)); }

struct B3 { f16x8 r, z, n; };
// LDS weight read: chunk layout [chunk][gate(3)][jj(8)][32 halves].
// Lane reads jj = l15&7 (lanes 8-15 duplicate -> junk results in discarded cols).
__device__ __forceinline__ B3 ldsB(const _Float16* wl, int chunk, int jj, int kq) {
  B3 o;
  const _Float16* p = wl + chunk * 768 + jj * 32 + kq;
  o.r = *(const f16x8*)p;
  o.z = *(const f16x8*)(p + 256);
  o.n = *(const f16x8*)(p + 512);
  return o;
}

__global__ void prep_x0(const int* __restrict__ texts, const float* __restrict__ emb,
                        _Float16* __restrict__ x0) {
  const size_t N = (size_t)T_STEPS * BB * EP;
  const size_t stride = (size_t)gridDim.x * blockDim.x;
  for (size_t i = (size_t)blockIdx.x * blockDim.x + threadIdx.x; i < N; i += stride) {
    int e = (int)(i % EP);
    size_t tb = i / EP;
    float v = 0.f;
    if (e < EE) v = emb[(size_t)texts[tb] * EE + e];
    x0[i] = (_Float16)v;
  }
}

__global__ void prep_b(const float* __restrict__ bih0, const float* __restrict__ bhh0,
                       const float* __restrict__ bih1, const float* __restrict__ bhh1,
                       float* __restrict__ bias0, float* __restrict__ bias1) {
  int i = blockIdx.x * blockDim.x + threadIdx.x;
  if (i < HH) {
    bias0[i]        = bih0[i] + bhh0[i];
    bias0[512 + i]  = bih0[512 + i] + bhh0[512 + i];
    bias0[1024 + i] = bih0[1024 + i];
    bias0[1536 + i] = bhh0[1024 + i];
    bias1[i]        = bih1[i] + bhh1[i];
    bias1[512 + i]  = bih1[512 + i] + bhh1[512 + i];
    bias1[1024 + i] = bih1[1024 + i];
    bias1[1536 + i] = bhh1[1024 + i];
  }
}

// 128 WGs x 256 threads. WG 0..63 = layer0 (8-col slices), 64..127 = layer1.
// WEIGHTS LIVE IN LDS (filled once from fp32 inputs): per-stage weight reads
// are ds_read_b128 — no global traffic, no serialized L2/HBM round-trips
// (round-10 probe: the global weight-load pattern alone cost ~93 us/stage).
__global__ __launch_bounds__(256, 1) void gru_persistent(
    const _Float16* __restrict__ x0,
    const float* __restrict__ Wih0, const float* __restrict__ Whh0,
    const float* __restrict__ Wih1, const float* __restrict__ Whh1,
    const float* __restrict__ bias0, const float* __restrict__ bias1,
    _Float16* h1ring, _Float16* h2buf, float* pooled,
    int* flags0, int* flags1)
{
  const int wg   = blockIdx.x;
  const int L    = wg >> 6;
  const int w    = wg & 63;
  const int jb   = w * NCOL;
  const int tid  = threadIdx.x;
  const int bsub = tid >> 6;          // wave index: owns batch rows 16*bsub..+15
  const int lane = tid & 63;
  const int quad = lane >> 4;
  const int l15  = lane & 15;
  const int jj   = l15 & 7;           // real column within slice (lanes 8-15 dup)
  const int brow = bsub * 16 + l15;   // A-operand row (batch)
  const int j    = jb + jj;           // output column (for bias)
  const int kq   = quad * 8;
  const int hoff = brow * (HH * 2) + quad * 16;   // byte voffset into an h slot

  __shared__ _Float16 wlds[24576];          // 49152 B: L1 32 chunks x 768 halves
  __shared__ _Float16 tile[2][4][16][NCOL]; // 2048 B, wave-private b x j tiles

  // ---- one-time LDS weight fill from fp32 globals ----
  if (L == 0) {
    // chunks 0..9 = W0x (K=320, cols >=300 zero), 10..25 = W0h (K=512)
    for (int idx = tid; idx < 26 * 96; idx += 256) {
      int q = idx & 3, j8 = (idx >> 2) & 7, g = (idx >> 5) % 3, ch = idx / 96;
      int row = g * 512 + jb + j8;
      _Float16* dst = wlds + ch * 768 + g * 256 + j8 * 32 + q * 8;
      if (ch < 10) {
        int colb = ch * 32 + q * 8;
        #pragma unroll
        for (int e = 0; e < 8; ++e) {
          int col = colb + e;
          dst[e] = (col < EE) ? (_Float16)Wih0[(size_t)row * EE + col] : (_Float16)0.f;
        }
      } else {
        int colb = (ch - 10) * 32 + q * 8;
        #pragma unroll
        for (int e = 0; e < 8; ++e)
          dst[e] = (_Float16)Whh0[(size_t)row * HH + colb + e];
      }
    }
  } else {
    // chunks 0..15 = W1x, 16..31 = W1h (both K=512)
    for (int idx = tid; idx < 32 * 96; idx += 256) {
      int q = idx & 3, j8 = (idx >> 2) & 7, g = (idx >> 5) % 3, ch = idx / 96;
      int row = g * 512 + jb + j8;
      const float* src = (ch < 16) ? Wih1 : Whh1;
      int colb = ((ch < 16) ? ch : ch - 16) * 32 + q * 8;
      _Float16* dst = wlds + ch * 768 + g * 256 + j8 * 32 + q * 8;
      #pragma unroll
      for (int e = 0; e < 8; ++e)
        dst[e] = (_Float16)src[(size_t)row * HH + colb + e];
    }
  }
  __syncthreads();

  if (L == 0) {
    const float br = bias0[j], bz = bias0[512 + j];
    const float bnx = bias0[1024 + j], bnh = bias0[1536 + j];
    const int xoff = brow * (EP * 2) + quad * 16;
    i32x4 xq[10];
    loadx10_wait(xq, x0, xoff);       // stage-0 x
    for (int s = 0; s < T_STEPS; ++s) {
      f32x4 aR = {0.f,0.f,0.f,0.f}, aZ = {0.f,0.f,0.f,0.f};
      f32x4 aNX = {0.f,0.f,0.f,0.f}, aNH = {0.f,0.f,0.f,0.f};
      #pragma unroll 5
      for (int c = 0; c < 10; ++c) {   // x-part first (no cross-WG dependency)
        f16x8 a = fragq(xq[c]);
        B3 bb = ldsB(wlds, c, jj, kq);
        aR = mf(a, bb.r, aR); aZ = mf(a, bb.z, aZ); aNX = mf(a, bb.n, aNX);
      }
      // edge A: all h1[s-1] published; edge B: ring slot free (L1 done s-RING)
      wg_wait2((s >= 1)    ? flags0 + (size_t)(s - 1) * NWG    : nullptr,
               (s >= RING) ? flags1 + (size_t)(s - RING) * NWG : nullptr);
      if (s >= 1) {
        HMat hA;
        load16_mall(hA, h1ring + ((s - 1) & (RING - 1)) * HB, hoff);
        #pragma unroll 4
        for (int c = 0; c < 16; ++c) {
          f16x8 a = fragq(hA.q[c]);
          B3 bb = ldsB(wlds, 10 + c, jj, kq);
          aR = mf(a, bb.r, aR); aZ = mf(a, bb.z, aZ); aNH = mf(a, bb.n, aNH);
        }
      }

      _Float16 (*tc)[NCOL] = tile[s & 1][bsub];
      _Float16 (*tp)[NCOL] = tile[(s + 1) & 1][bsub];
      #pragma unroll
      for (int rg = 0; rg < 4; ++rg) {
        const int rr = quad * 4 + rg;           // C/D row = quad*4+reg
        float r = sigf(aR[rg] + br);
        float z = sigf(aZ[rg] + bz);
        float n = tanhf(aNX[rg] + bnx + r * (aNH[rg] + bnh));
        float hp = (s >= 1) ? (float)tp[rr][jj] : 0.f;
        if (l15 < 8) tc[rr][l15] = (_Float16)((1.f - z) * n + z * hp);
      }
      if (lane < 16) {                          // publish own 16 rows (16B each)
        f16x8 v = *(const f16x8*)&tc[lane][0];
        st16_mall(h1ring + (s & (RING - 1)) * HB + (size_t)(bsub * 16 + lane) * HH + jb, v);
      }
      __builtin_amdgcn_s_waitcnt(0);            // h at MALL before flag
      if (lane == 0) st1_dev((char*)(flags0 + (size_t)s * NWG + w) + bsub, 1);
      if (s + 1 < T_STEPS)                      // batched x prefetch
        loadx10_wait(xq, x0 + (size_t)(s + 1) * BB * EP, xoff);
    }
  } else {
    const float br = bias1[j], bz = bias1[512 + j];
    const float bnx = bias1[1024 + j], bnh = bias1[1536 + j];
    for (int t = 0; t < T_STEPS; ++t) {
      f32x4 aR = {0.f,0.f,0.f,0.f}, aZ = {0.f,0.f,0.f,0.f};
      f32x4 aNX = {0.f,0.f,0.f,0.f}, aNH = {0.f,0.f,0.f,0.f};
      // phase 1: self-recurrence (h2[t-1]) while L0 finishes h1[t]
      wg_wait2((t >= 1) ? flags1 + (size_t)(t - 1) * NWG : nullptr, nullptr);
      if (t >= 1) {
        HMat A2;
        load16_mall(A2, h2buf + ((t - 1) & 1) * HB, hoff);
        #pragma unroll 4
        for (int c = 0; c < 16; ++c) {
          f16x8 a = fragq(A2.q[c]);
          B3 bb = ldsB(wlds, 16 + c, jj, kq);
          aR = mf(a, bb.r, aR); aZ = mf(a, bb.z, aZ); aNH = mf(a, bb.n, aNH);
        }
      }
      // phase 2: h1[t] from layer 0 (L0 runs ahead -> usually already set)
      wg_wait2(flags0 + (size_t)t * NWG, nullptr);
      {
        HMat A1;
        load16_mall(A1, h1ring + (t & (RING - 1)) * HB, hoff);
        #pragma unroll 4
        for (int c = 0; c < 16; ++c) {
          f16x8 a = fragq(A1.q[c]);
          B3 bb = ldsB(wlds, c, jj, kq);
          aR = mf(a, bb.r, aR); aZ = mf(a, bb.z, aZ); aNX = mf(a, bb.n, aNX);
        }
      }

      _Float16 (*tc)[NCOL] = tile[t & 1][bsub];
      _Float16 (*tp)[NCOL] = tile[(t + 1) & 1][bsub];
      #pragma unroll
      for (int rg = 0; rg < 4; ++rg) {
        const int rr = quad * 4 + rg;
        float r = sigf(aR[rg] + br);
        float z = sigf(aZ[rg] + bz);
        float n = tanhf(aNX[rg] + bnx + r * (aNH[rg] + bnh));
        float hp = (t >= 1) ? (float)tp[rr][jj] : 0.f;
        if (l15 < 8) tc[rr][l15] = (_Float16)((1.f - z) * n + z * hp);
      }
      if (lane < 16) {
        f16x8 v = *(const f16x8*)&tc[lane][0];
        st16_mall(h2buf + (t & 1) * HB + (size_t)(bsub * 16 + lane) * HH + jb, v);
      }
      __builtin_amdgcn_s_waitcnt(0);
      if (lane == 0) st1_dev((char*)(flags1 + (size_t)t * NWG + w) + bsub, 1);
      // pooled partial (off critical path): per-wave column sums of own tile
      if (lane < 8) {
        float sum = 0.f;
        #pragma unroll
        for (int r = 0; r < 16; ++r) sum += (float)tc[r][lane];
        atomicAdd(pooled + (size_t)t * HH + jb + lane, sum);   // raw sum; /64 in FC
      }
    }
  }
}

__global__ void fc_kernel(const float* __restrict__ pooled, const float* __restrict__ fcW,
                          const float* __restrict__ fcb, float* __restrict__ out) {
  const int t = blockIdx.x;
  const int lane = threadIdx.x;  // 64 = one wave
  float a0 = 0.f, a1 = 0.f, a2 = 0.f, a3 = 0.f, a4 = 0.f;
  for (int jj = lane; jj < HH; jj += 64) {
    float p = pooled[(size_t)t * HH + jj];
    a0 += p * fcW[jj];
    a1 += p * fcW[512 + jj];
    a2 += p * fcW[1024 + jj];
    a3 += p * fcW[1536 + jj];
    a4 += p * fcW[2048 + jj];
  }
  #pragma unroll
  for (int off = 32; off > 0; off >>= 1) {
    a0 += __shfl_down(a0, off, 64);
    a1 += __shfl_down(a1, off, 64);
    a2 += __shfl_down(a2, off, 64);
    a3 += __shfl_down(a3, off, 64);
    a4 += __shfl_down(a4, off, 64);
  }
  if (lane == 0) {
    const float sc = 1.f / 64.f;
    out[t * 5 + 0] = a0 * sc + fcb[0];
    out[t * 5 + 1] = a1 * sc + fcb[1];
    out[t * 5 + 2] = a2 * sc + fcb[2];
    out[t * 5 + 3] = a3 * sc + fcb[3];
    out[t * 5 + 4] = a4 * sc + fcb[4];
  }
}

extern "C" void kernel_launch(void* const* d_in, const int* in_sizes, int n_in,
                              void* d_out, int out_size, void* d_ws, size_t ws_size,
                              hipStream_t stream) {
  const int*   texts = (const int*)  d_in[0];
  const float* emb   = (const float*)d_in[1];
  const float* Wih0  = (const float*)d_in[2];
  const float* Whh0  = (const float*)d_in[3];
  const float* bih0  = (const float*)d_in[4];
  const float* bhh0  = (const float*)d_in[5];
  const float* Wih1  = (const float*)d_in[6];
  const float* Whh1  = (const float*)d_in[7];
  const float* bih1  = (const float*)d_in[8];
  const float* bhh1  = (const float*)d_in[9];
  const float* fcW   = (const float*)d_in[10];
  const float* fcb   = (const float*)d_in[11];
  float* out = (float*)d_out;

  char* ws = (char*)d_ws;
  int*      flags0 = (int*)ws;                        // 131072 B [512][64] int
  int*      flags1 = (int*)(ws + 131072);             // 131072 B
  float*    pooled = (float*)(ws + 262144);           // 1048576 B [512][512] f32
  _Float16* h1ring = (_Float16*)(ws + 1310720);       // 262144 B (4 x 64x512 f16)
  _Float16* h2buf  = (_Float16*)(ws + 1572864);       // 131072 B (2 slots)
  _Float16* x0     = (_Float16*)(ws + 1703936);       // 20971520 B [512][64][320]
  float*    bias0  = (float*)(ws + 22675456);         // 8192 B (r,z,nx,nh)
  float*    bias1  = (float*)(ws + 22683648);         // 8192 B
  // total ws use: 22691840 B

  hipMemsetAsync(ws, 0, 1310720, stream);  // flags0 + flags1 + pooled = zeros
  prep_x0<<<4096, 256, 0, stream>>>(texts, emb, x0);
  prep_b<<<2, 256, 0, stream>>>(bih0, bhh0, bih1, bhh1, bias0, bias1);
  gru_persistent<<<128, 256, 0, stream>>>(x0, Wih0, Whh0, Wih1, Whh1, bias0, bias1,
                                          h1ring, h2buf, pooled, flags0, flags1);
  fc_kernel<<<512, 64, 0, stream>>>(pooled, fcW, fcb, out);
}

// Round 12
// 6457.260 us; speedup vs baseline: 4.7390x; 1.4672x over previous
//
#include <hip/hip_runtime.h>

#define T_STEPS 512
#define BB 64
#define EE 300
#define EP 320
#define HH 512
#define HB (BB*HH)   // halves per h slot
#define RING 8
#define NCOL 8       // output columns per WG
#define NWG 64       // WGs per layer

typedef _Float16 f16x8 __attribute__((ext_vector_type(8)));
typedef float f32x4 __attribute__((ext_vector_type(4)));
typedef int i32x4 __attribute__((ext_vector_type(4)));

__device__ __forceinline__ f32x4 mf(f16x8 a, f16x8 b, f32x4 c) {
  return __builtin_amdgcn_mfma_f32_16x16x32_f16(a, b, c, 0, 0, 0);
}

struct HMat { i32x4 q[16]; };   // 64 VGPRs: one lane's 16 A-fragments of a 64x512 f16 matrix

// 16 back-to-back MALL (sc1) 16B loads + FULL drain in ONE asm block
// (in-flight regs never escape a block — round-4 lesson). Proven h-data path.
#define LOADS16_MALL                                                 \
    "global_load_dwordx4 %0,  %16, %17 sc1\n\t"                      \
    "global_load_dwordx4 %1,  %16, %17 offset:64 sc1\n\t"            \
    "global_load_dwordx4 %2,  %16, %17 offset:128 sc1\n\t"           \
    "global_load_dwordx4 %3,  %16, %17 offset:192 sc1\n\t"           \
    "global_load_dwordx4 %4,  %16, %17 offset:256 sc1\n\t"           \
    "global_load_dwordx4 %5,  %16, %17 offset:320 sc1\n\t"           \
    "global_load_dwordx4 %6,  %16, %17 offset:384 sc1\n\t"           \
    "global_load_dwordx4 %7,  %16, %17 offset:448 sc1\n\t"           \
    "global_load_dwordx4 %8,  %16, %17 offset:512 sc1\n\t"           \
    "global_load_dwordx4 %9,  %16, %17 offset:576 sc1\n\t"           \
    "global_load_dwordx4 %10, %16, %17 offset:640 sc1\n\t"           \
    "global_load_dwordx4 %11, %16, %17 offset:704 sc1\n\t"           \
    "global_load_dwordx4 %12, %16, %17 offset:768 sc1\n\t"           \
    "global_load_dwordx4 %13, %16, %17 offset:832 sc1\n\t"           \
    "global_load_dwordx4 %14, %16, %17 offset:896 sc1\n\t"           \
    "global_load_dwordx4 %15, %16, %17 offset:960 sc1\n\t"           \
    "s_waitcnt vmcnt(0)"

#define HM_OUTS(m) "=v"((m).q[0]), "=v"((m).q[1]), "=v"((m).q[2]), "=v"((m).q[3]),   \
                   "=v"((m).q[4]), "=v"((m).q[5]), "=v"((m).q[6]), "=v"((m).q[7]),   \
                   "=v"((m).q[8]), "=v"((m).q[9]), "=v"((m).q[10]), "=v"((m).q[11]), \
                   "=v"((m).q[12]), "=v"((m).q[13]), "=v"((m).q[14]), "=v"((m).q[15])

__device__ __forceinline__ void load16_mall(HMat& m, const void* base, int voff) {
  asm volatile(LOADS16_MALL : HM_OUTS(m) : "v"(voff), "s"(base) : "memory");
}

// batched x-prefetch: 10 plain cached loads + full drain (x0 is immutable)
__device__ __forceinline__ void loadx10_wait(i32x4* xq, const void* base, int voff) {
  asm volatile(
    "global_load_dwordx4 %0, %10, %11\n\t"
    "global_load_dwordx4 %1, %10, %11 offset:64\n\t"
    "global_load_dwordx4 %2, %10, %11 offset:128\n\t"
    "global_load_dwordx4 %3, %10, %11 offset:192\n\t"
    "global_load_dwordx4 %4, %10, %11 offset:256\n\t"
    "global_load_dwordx4 %5, %10, %11 offset:320\n\t"
    "global_load_dwordx4 %6, %10, %11 offset:384\n\t"
    "global_load_dwordx4 %7, %10, %11 offset:448\n\t"
    "global_load_dwordx4 %8, %10, %11 offset:512\n\t"
    "global_load_dwordx4 %9, %10, %11 offset:576\n\t"
    "s_waitcnt vmcnt(0)"
    : "=v"(xq[0]), "=v"(xq[1]), "=v"(xq[2]), "=v"(xq[3]), "=v"(xq[4]),
      "=v"(xq[5]), "=v"(xq[6]), "=v"(xq[7]), "=v"(xq[8]), "=v"(xq[9])
    : "v"(voff), "s"(base) : "memory");
}

__device__ __forceinline__ f16x8 fragq(i32x4 q) {
  union { i32x4 i; f16x8 v; } x; x.i = q; return x.v;
}

// h-tile publish to MALL (proven pair with sc1 loads)
__device__ __forceinline__ void st16_mall(void* p, f16x8 v) {
  i32x4 iv;
  __builtin_memcpy(&iv, &v, 16);
  asm volatile("global_store_dwordx4 %0, %1, off sc0 sc1" :: "v"(p), "v"(iv) : "memory");
}

// device-scope flag word publish / poll
__device__ __forceinline__ void st4_dev(int* p, int v) {
  asm volatile("global_store_dword %0, %1, off sc0 sc1" :: "v"(p), "v"(v) : "memory");
}
__device__ __forceinline__ int ld4_dev(const int* p) {
  int r;
  asm volatile("global_load_dword %0, %1, off sc1\n\ts_waitcnt vmcnt(0)"
               : "=v"(r) : "v"(p) : "memory");
  return r;
}

// WG wait on monotone value flags (one word per producer WG, 64B apart).
// Wave 0 polls edge A (64 words, one per lane), wave 1 edge B; barrier releases.
__device__ __forceinline__ void wg_waitv(const int* fA, int tA, const int* fB, int tB) {
  const int wv = threadIdx.x >> 6, lane = threadIdx.x & 63;
  if (wv == 0 && fA) {
    const int* q = fA + lane * 16;
    while (!__all(ld4_dev(q) >= tA)) {}
  } else if (wv == 1 && fB) {
    const int* q = fB + lane * 16;
    while (!__all(ld4_dev(q) >= tB)) {}
  }
  __syncthreads();
}

__device__ __forceinline__ float sigf(float x) { return 1.f / (1.f + __expf(-x)); }

struct B3 { f16x8 r, z, n; };
// LDS weight read: chunk layout [chunk][gate(3)][jj(8)][32 halves].
// Lane reads jj = l15&7 (lanes 8-15 duplicate -> identical discarded cols).
__device__ __forceinline__ B3 ldsB(const _Float16* wl, int chunk, int jj, int kq) {
  B3 o;
  const _Float16* p = wl + chunk * 768 + jj * 32 + kq;
  o.r = *(const f16x8*)p;
  o.z = *(const f16x8*)(p + 256);
  o.n = *(const f16x8*)(p + 512);
  return o;
}

__global__ void prep_x0(const int* __restrict__ texts, const float* __restrict__ emb,
                        _Float16* __restrict__ x0) {
  const size_t N = (size_t)T_STEPS * BB * EP;
  const size_t stride = (size_t)gridDim.x * blockDim.x;
  for (size_t i = (size_t)blockIdx.x * blockDim.x + threadIdx.x; i < N; i += stride) {
    int e = (int)(i % EP);
    size_t tb = i / EP;
    float v = 0.f;
    if (e < EE) v = emb[(size_t)texts[tb] * EE + e];
    x0[i] = (_Float16)v;
  }
}

__global__ void prep_b(const float* __restrict__ bih0, const float* __restrict__ bhh0,
                       const float* __restrict__ bih1, const float* __restrict__ bhh1,
                       float* __restrict__ bias0, float* __restrict__ bias1) {
  int i = blockIdx.x * blockDim.x + threadIdx.x;
  if (i < HH) {
    bias0[i]        = bih0[i] + bhh0[i];
    bias0[512 + i]  = bih0[512 + i] + bhh0[512 + i];
    bias0[1024 + i] = bih0[1024 + i];
    bias0[1536 + i] = bhh0[1024 + i];
    bias1[i]        = bih1[i] + bhh1[i];
    bias1[512 + i]  = bih1[512 + i] + bhh1[512 + i];
    bias1[1024 + i] = bih1[1024 + i];
    bias1[1536 + i] = bhh1[1024 + i];
  }
}

// 128 WGs x 256 threads. WG 0..63 = layer0 (8-col slices), 64..127 = layer1.
// Weights LDS-resident (round-11 win). This round: value flags on exclusive
// lines + L1's A1/x-part moved off the critical path (prefetched one step
// ahead while the self-recurrence handoff is the only serialized edge).
__global__ __launch_bounds__(256, 1) void gru_persistent(
    const _Float16* __restrict__ x0,
    const float* __restrict__ Wih0, const float* __restrict__ Whh0,
    const float* __restrict__ Wih1, const float* __restrict__ Whh1,
    const float* __restrict__ bias0, const float* __restrict__ bias1,
    _Float16* h1ring, _Float16* h2buf, float* pooled,
    int* flags0, int* flags1)
{
  const int wg   = blockIdx.x;
  const int L    = wg >> 6;
  const int w    = wg & 63;
  const int jb   = w * NCOL;
  const int tid  = threadIdx.x;
  const int bsub = tid >> 6;          // wave index: owns batch rows 16*bsub..+15
  const int lane = tid & 63;
  const int quad = lane >> 4;
  const int l15  = lane & 15;
  const int jj   = l15 & 7;           // real column within slice (lanes 8-15 dup)
  const int brow = bsub * 16 + l15;   // A-operand row (batch)
  const int j    = jb + jj;           // output column (for bias)
  const int kq   = quad * 8;
  const int hoff = brow * (HH * 2) + quad * 16;   // byte voffset into an h slot

  __shared__ _Float16 wlds[24576];          // 49152 B: 32 chunks x 768 halves
  __shared__ _Float16 tile[2][4][16][NCOL]; // 2048 B, wave-private b x j tiles

  // ---- one-time LDS weight fill from fp32 globals ----
  if (L == 0) {
    // chunks 0..9 = W0x (K=320, cols >=300 zero), 10..25 = W0h (K=512)
    for (int idx = tid; idx < 26 * 96; idx += 256) {
      int q = idx & 3, j8 = (idx >> 2) & 7, g = (idx >> 5) % 3, ch = idx / 96;
      int row = g * 512 + jb + j8;
      _Float16* dst = wlds + ch * 768 + g * 256 + j8 * 32 + q * 8;
      if (ch < 10) {
        int colb = ch * 32 + q * 8;
        #pragma unroll
        for (int e = 0; e < 8; ++e) {
          int col = colb + e;
          dst[e] = (col < EE) ? (_Float16)Wih0[(size_t)row * EE + col] : (_Float16)0.f;
        }
      } else {
        int colb = (ch - 10) * 32 + q * 8;
        #pragma unroll
        for (int e = 0; e < 8; ++e)
          dst[e] = (_Float16)Whh0[(size_t)row * HH + colb + e];
      }
    }
  } else {
    // chunks 0..15 = W1x, 16..31 = W1h (both K=512)
    for (int idx = tid; idx < 32 * 96; idx += 256) {
      int q = idx & 3, j8 = (idx >> 2) & 7, g = (idx >> 5) % 3, ch = idx / 96;
      int row = g * 512 + jb + j8;
      const float* src = (ch < 16) ? Wih1 : Whh1;
      int colb = ((ch < 16) ? ch : ch - 16) * 32 + q * 8;
      _Float16* dst = wlds + ch * 768 + g * 256 + j8 * 32 + q * 8;
      #pragma unroll
      for (int e = 0; e < 8; ++e)
        dst[e] = (_Float16)src[(size_t)row * HH + colb + e];
    }
  }
  __syncthreads();

  if (L == 0) {
    const float br = bias0[j], bz = bias0[512 + j];
    const float bnx = bias0[1024 + j], bnh = bias0[1536 + j];
    const int xoff = brow * (EP * 2) + quad * 16;
    i32x4 xq[10];
    loadx10_wait(xq, x0, xoff);       // stage-0 x
    for (int s = 0; s < T_STEPS; ++s) {
      // x-part first — off critical path (no cross-WG dependency)
      f32x4 aR = {0.f,0.f,0.f,0.f}, aZ = {0.f,0.f,0.f,0.f};
      f32x4 aNX = {0.f,0.f,0.f,0.f}, aNH = {0.f,0.f,0.f,0.f};
      #pragma unroll 5
      for (int c = 0; c < 10; ++c) {
        f16x8 a = fragq(xq[c]);
        B3 bb = ldsB(wlds, c, jj, kq);
        aR = mf(a, bb.r, aR); aZ = mf(a, bb.z, aZ); aNX = mf(a, bb.n, aNX);
      }
      // one wait: own-layer all-to-all (critical) + ring throttle (slack)
      wg_waitv((s >= 1)    ? flags0 : nullptr, s,
               (s >= RING) ? flags1 : nullptr, s - RING + 1);
      if (s >= 1) {
        HMat hA;
        load16_mall(hA, h1ring + ((s - 1) & (RING - 1)) * HB, hoff);
        #pragma unroll 4
        for (int c = 0; c < 16; ++c) {
          f16x8 a = fragq(hA.q[c]);
          B3 bb = ldsB(wlds, 10 + c, jj, kq);
          aR = mf(a, bb.r, aR); aZ = mf(a, bb.z, aZ); aNH = mf(a, bb.n, aNH);
        }
      }

      _Float16 (*tc)[NCOL] = tile[s & 1][bsub];
      _Float16 (*tp)[NCOL] = tile[(s + 1) & 1][bsub];
      #pragma unroll
      for (int rg = 0; rg < 4; ++rg) {
        const int rr = quad * 4 + rg;           // C/D row = quad*4+reg
        float r = sigf(aR[rg] + br);
        float z = sigf(aZ[rg] + bz);
        float n = tanhf(aNX[rg] + bnx + r * (aNH[rg] + bnh));
        float hp = (s >= 1) ? (float)tp[rr][jj] : 0.f;
        if (l15 < 8) tc[rr][l15] = (_Float16)((1.f - z) * n + z * hp);
      }
      if (lane < 16) {                          // publish own 16 rows (16B each)
        f16x8 v = *(const f16x8*)&tc[lane][0];
        st16_mall(h1ring + (s & (RING - 1)) * HB + (size_t)(bsub * 16 + lane) * HH + jb, v);
      }
      __builtin_amdgcn_s_waitcnt(0);            // own h stores at MALL
      __syncthreads();                          // all 4 waves drained
      if (tid == 0) st4_dev(flags0 + w * 16, s + 1);   // one word, own line
      if (s + 1 < T_STEPS)                      // batched x prefetch (off-path)
        loadx10_wait(xq, x0 + (size_t)(s + 1) * BB * EP, xoff);
    }
  } else {
    const float br = bias1[j], bz = bias1[512 + j];
    const float bnx = bias1[1024 + j], bnh = bias1[1536 + j];
    // preloop: prefetch h1[0] and its x-part accumulators (off critical path)
    f32x4 xR = {0.f,0.f,0.f,0.f}, xZ = {0.f,0.f,0.f,0.f}, xN = {0.f,0.f,0.f,0.f};
    {
      wg_waitv(flags0, 1, nullptr, 0);
      HMat A1;
      load16_mall(A1, h1ring, hoff);
      #pragma unroll 4
      for (int c = 0; c < 16; ++c) {
        f16x8 a = fragq(A1.q[c]);
        B3 bb = ldsB(wlds, c, jj, kq);
        xR = mf(a, bb.r, xR); xZ = mf(a, bb.z, xZ); xN = mf(a, bb.n, xN);
      }
    }
    for (int t = 0; t < T_STEPS; ++t) {
      // CRITICAL edge: own-layer self-recurrence handoff
      wg_waitv((t >= 1) ? flags1 : nullptr, t, nullptr, 0);
      f32x4 hR = {0.f,0.f,0.f,0.f}, hZ = {0.f,0.f,0.f,0.f}, hN = {0.f,0.f,0.f,0.f};
      if (t >= 1) {
        HMat A2;
        load16_mall(A2, h2buf + ((t - 1) & 1) * HB, hoff);
        #pragma unroll 4
        for (int c = 0; c < 16; ++c) {
          f16x8 a = fragq(A2.q[c]);
          B3 bb = ldsB(wlds, 16 + c, jj, kq);
          hR = mf(a, bb.r, hR); hZ = mf(a, bb.z, hZ); hN = mf(a, bb.n, hN);
        }
      }

      _Float16 (*tc)[NCOL] = tile[t & 1][bsub];
      _Float16 (*tp)[NCOL] = tile[(t + 1) & 1][bsub];
      #pragma unroll
      for (int rg = 0; rg < 4; ++rg) {
        const int rr = quad * 4 + rg;
        float r = sigf(xR[rg] + hR[rg] + br);
        float z = sigf(xZ[rg] + hZ[rg] + bz);
        float n = tanhf(xN[rg] + bnx + r * (hN[rg] + bnh));
        float hp = (t >= 1) ? (float)tp[rr][jj] : 0.f;
        if (l15 < 8) tc[rr][l15] = (_Float16)((1.f - z) * n + z * hp);
      }
      if (lane < 16) {
        f16x8 v = *(const f16x8*)&tc[lane][0];
        st16_mall(h2buf + (t & 1) * HB + (size_t)(bsub * 16 + lane) * HH + jb, v);
      }
      __builtin_amdgcn_s_waitcnt(0);
      __syncthreads();
      if (tid == 0) st4_dev(flags1 + w * 16, t + 1);

      // off-path: pooled partial, then prefetch h1[t+1] + its x-part MFMAs
      if (lane < 8) {
        float sum = 0.f;
        #pragma unroll
        for (int r = 0; r < 16; ++r) sum += (float)tc[r][lane];
        atomicAdd(pooled + (size_t)t * HH + jb + lane, sum);   // raw sum; /64 in FC
      }
      if (t + 1 < T_STEPS) {
        wg_waitv(flags0, t + 2, nullptr, 0);    // L0 runs RING ahead: ~instant
        HMat A1;
        load16_mall(A1, h1ring + ((t + 1) & (RING - 1)) * HB, hoff);
        xR = (f32x4){0.f,0.f,0.f,0.f}; xZ = (f32x4){0.f,0.f,0.f,0.f};
        xN = (f32x4){0.f,0.f,0.f,0.f};
        #pragma unroll 4
        for (int c = 0; c < 16; ++c) {
          f16x8 a = fragq(A1.q[c]);
          B3 bb = ldsB(wlds, c, jj, kq);
          xR = mf(a, bb.r, xR); xZ = mf(a, bb.z, xZ); xN = mf(a, bb.n, xN);
        }
      }
    }
  }
}

__global__ void fc_kernel(const float* __restrict__ pooled, const float* __restrict__ fcW,
                          const float* __restrict__ fcb, float* __restrict__ out) {
  const int t = blockIdx.x;
  const int lane = threadIdx.x;  // 64 = one wave
  float a0 = 0.f, a1 = 0.f, a2 = 0.f, a3 = 0.f, a4 = 0.f;
  for (int jj = lane; jj < HH; jj += 64) {
    float p = pooled[(size_t)t * HH + jj];
    a0 += p * fcW[jj];
    a1 += p * fcW[512 + jj];
    a2 += p * fcW[1024 + jj];
    a3 += p * fcW[1536 + jj];
    a4 += p * fcW[2048 + jj];
  }
  #pragma unroll
  for (int off = 32; off > 0; off >>= 1) {
    a0 += __shfl_down(a0, off, 64);
    a1 += __shfl_down(a1, off, 64);
    a2 += __shfl_down(a2, off, 64);
    a3 += __shfl_down(a3, off, 64);
    a4 += __shfl_down(a4, off, 64);
  }
  if (lane == 0) {
    const float sc = 1.f / 64.f;
    out[t * 5 + 0] = a0 * sc + fcb[0];
    out[t * 5 + 1] = a1 * sc + fcb[1];
    out[t * 5 + 2] = a2 * sc + fcb[2];
    out[t * 5 + 3] = a3 * sc + fcb[3];
    out[t * 5 + 4] = a4 * sc + fcb[4];
  }
}

extern "C" void kernel_launch(void* const* d_in, const int* in_sizes, int n_in,
                              void* d_out, int out_size, void* d_ws, size_t ws_size,
                              hipStream_t stream) {
  const int*   texts = (const int*)  d_in[0];
  const float* emb   = (const float*)d_in[1];
  const float* Wih0  = (const float*)d_in[2];
  const float* Whh0  = (const float*)d_in[3];
  const float* bih0  = (const float*)d_in[4];
  const float* bhh0  = (const float*)d_in[5];
  const float* Wih1  = (const float*)d_in[6];
  const float* Whh1  = (const float*)d_in[7];
  const float* bih1  = (const float*)d_in[8];
  const float* bhh1  = (const float*)d_in[9];
  const float* fcW   = (const float*)d_in[10];
  const float* fcb   = (const float*)d_in[11];
  float* out = (float*)d_out;

  char* ws = (char*)d_ws;
  int*      flags0 = (int*)ws;                        // 4096 B: 64 words, 64B apart
  int*      flags1 = (int*)(ws + 4096);               // 4096 B
  float*    pooled = (float*)(ws + 8192);             // 1048576 B [512][512] f32
  _Float16* h1ring = (_Float16*)(ws + 1056768);       // 524288 B (8 x 64x512 f16)
  _Float16* h2buf  = (_Float16*)(ws + 1581056);       // 131072 B (2 slots)
  _Float16* x0     = (_Float16*)(ws + 1712128);       // 20971520 B [512][64][320]
  float*    bias0  = (float*)(ws + 22683648);         // 8192 B (r,z,nx,nh)
  float*    bias1  = (float*)(ws + 22691840);         // 8192 B
  // total ws use: 22700032 B

  hipMemsetAsync(ws, 0, 1056768, stream);  // flags0 + flags1 + pooled = zeros
  prep_x0<<<4096, 256, 0, stream>>>(texts, emb, x0);
  prep_b<<<2, 256, 0, stream>>>(bih0, bhh0, bih1, bhh1, bias0, bias1);
  gru_persistent<<<128, 256, 0, stream>>>(x0, Wih0, Whh0, Wih1, Whh1, bias0, bias1,
                                          h1ring, h2buf, pooled, flags0, flags1);
  fc_kernel<<<512, 64, 0, stream>>>(pooled, fcW, fcb, out);
}

// Round 13
// 6416.795 us; speedup vs baseline: 4.7689x; 1.0063x over previous
//
#include <hip/hip_runtime.h>

#define T_STEPS 512
#define BB 64
#define EE 300
#define EP 320
#define HH 512
#define HB (BB*HH)   // halves per h slot
#define RING 8
#define NCOL 8       // output columns per WG
#define NWG 64       // WGs per layer

typedef _Float16 f16x8 __attribute__((ext_vector_type(8)));
typedef float f32x4 __attribute__((ext_vector_type(4)));
typedef int i32x4 __attribute__((ext_vector_type(4)));

__device__ __forceinline__ f32x4 mf(f16x8 a, f16x8 b, f32x4 c) {
  return __builtin_amdgcn_mfma_f32_16x16x32_f16(a, b, c, 0, 0, 0);
}

struct HMat { i32x4 q[16]; };   // 64 VGPRs: one lane's 16 A-fragments of a 64x512 f16 matrix

// 16 back-to-back MALL (sc1) 16B loads + FULL drain in ONE asm block
// (in-flight regs never escape a block — round-4 lesson). Proven h-data path.
#define LOADS16_MALL                                                 \
    "global_load_dwordx4 %0,  %16, %17 sc1\n\t"                      \
    "global_load_dwordx4 %1,  %16, %17 offset:64 sc1\n\t"            \
    "global_load_dwordx4 %2,  %16, %17 offset:128 sc1\n\t"           \
    "global_load_dwordx4 %3,  %16, %17 offset:192 sc1\n\t"           \
    "global_load_dwordx4 %4,  %16, %17 offset:256 sc1\n\t"           \
    "global_load_dwordx4 %5,  %16, %17 offset:320 sc1\n\t"           \
    "global_load_dwordx4 %6,  %16, %17 offset:384 sc1\n\t"           \
    "global_load_dwordx4 %7,  %16, %17 offset:448 sc1\n\t"           \
    "global_load_dwordx4 %8,  %16, %17 offset:512 sc1\n\t"           \
    "global_load_dwordx4 %9,  %16, %17 offset:576 sc1\n\t"           \
    "global_load_dwordx4 %10, %16, %17 offset:640 sc1\n\t"           \
    "global_load_dwordx4 %11, %16, %17 offset:704 sc1\n\t"           \
    "global_load_dwordx4 %12, %16, %17 offset:768 sc1\n\t"           \
    "global_load_dwordx4 %13, %16, %17 offset:832 sc1\n\t"           \
    "global_load_dwordx4 %14, %16, %17 offset:896 sc1\n\t"           \
    "global_load_dwordx4 %15, %16, %17 offset:960 sc1\n\t"           \
    "s_waitcnt vmcnt(0)"

#define HM_OUTS(m) "=v"((m).q[0]), "=v"((m).q[1]), "=v"((m).q[2]), "=v"((m).q[3]),   \
                   "=v"((m).q[4]), "=v"((m).q[5]), "=v"((m).q[6]), "=v"((m).q[7]),   \
                   "=v"((m).q[8]), "=v"((m).q[9]), "=v"((m).q[10]), "=v"((m).q[11]), \
                   "=v"((m).q[12]), "=v"((m).q[13]), "=v"((m).q[14]), "=v"((m).q[15])

__device__ __forceinline__ void load16_mall(HMat& m, const void* base, int voff) {
  asm volatile(LOADS16_MALL : HM_OUTS(m) : "v"(voff), "s"(base) : "memory");
}

// batched x-prefetch: 10 plain cached loads + full drain (x0 is immutable)
__device__ __forceinline__ void loadx10_wait(i32x4* xq, const void* base, int voff) {
  asm volatile(
    "global_load_dwordx4 %0, %10, %11\n\t"
    "global_load_dwordx4 %1, %10, %11 offset:64\n\t"
    "global_load_dwordx4 %2, %10, %11 offset:128\n\t"
    "global_load_dwordx4 %3, %10, %11 offset:192\n\t"
    "global_load_dwordx4 %4, %10, %11 offset:256\n\t"
    "global_load_dwordx4 %5, %10, %11 offset:320\n\t"
    "global_load_dwordx4 %6, %10, %11 offset:384\n\t"
    "global_load_dwordx4 %7, %10, %11 offset:448\n\t"
    "global_load_dwordx4 %8, %10, %11 offset:512\n\t"
    "global_load_dwordx4 %9, %10, %11 offset:576\n\t"
    "s_waitcnt vmcnt(0)"
    : "=v"(xq[0]), "=v"(xq[1]), "=v"(xq[2]), "=v"(xq[3]), "=v"(xq[4]),
      "=v"(xq[5]), "=v"(xq[6]), "=v"(xq[7]), "=v"(xq[8]), "=v"(xq[9])
    : "v"(voff), "s"(base) : "memory");
}

__device__ __forceinline__ f16x8 fragq(i32x4 q) {
  union { i32x4 i; f16x8 v; } x; x.i = q; return x.v;
}

// h-tile publish to MALL (proven pair with sc1 loads)
__device__ __forceinline__ void st16_mall(void* p, f16x8 v) {
  i32x4 iv;
  __builtin_memcpy(&iv, &v, 16);
  asm volatile("global_store_dwordx4 %0, %1, off sc0 sc1" :: "v"(p), "v"(iv) : "memory");
}

// device-scope flag word publish / poll
__device__ __forceinline__ void st4_dev(int* p, int v) {
  asm volatile("global_store_dword %0, %1, off sc0 sc1" :: "v"(p), "v"(v) : "memory");
}
__device__ __forceinline__ int ld4_dev(const int* p) {
  int r;
  asm volatile("global_load_dword %0, %1, off sc1\n\ts_waitcnt vmcnt(0)"
               : "=v"(r) : "v"(p) : "memory");
  return r;
}

// WG wait on monotone value flags (one word per producer WG, 64B apart).
// Wave 0 polls edge A, wave 1 polls edge B CONCURRENTLY; one barrier releases.
// s_sleep backoff cuts MALL poll pressure (128 WGs x 64 lanes would otherwise
// stream continuous reads and inflate every fabric RT).
__device__ __forceinline__ void wg_waitv(const int* fA, int tA, const int* fB, int tB) {
  const int wv = threadIdx.x >> 6, lane = threadIdx.x & 63;
  if (wv == 0 && fA) {
    const int* q = fA + lane * 16;
    while (!__all(ld4_dev(q) >= tA)) __builtin_amdgcn_s_sleep(2);
  } else if (wv == 1 && fB) {
    const int* q = fB + lane * 16;
    while (!__all(ld4_dev(q) >= tB)) __builtin_amdgcn_s_sleep(2);
  }
  __syncthreads();
}

__device__ __forceinline__ float sigf(float x) { return 1.f / (1.f + __expf(-x)); }

struct B3 { f16x8 r, z, n; };
// LDS weight read: chunk layout [chunk][gate(3)][jj(8)][32 halves].
// Lane reads jj = l15&7 (lanes 8-15 duplicate -> identical discarded cols).
__device__ __forceinline__ B3 ldsB(const _Float16* wl, int chunk, int jj, int kq) {
  B3 o;
  const _Float16* p = wl + chunk * 768 + jj * 32 + kq;
  o.r = *(const f16x8*)p;
  o.z = *(const f16x8*)(p + 256);
  o.n = *(const f16x8*)(p + 512);
  return o;
}

__global__ void prep_x0(const int* __restrict__ texts, const float* __restrict__ emb,
                        _Float16* __restrict__ x0) {
  const size_t N = (size_t)T_STEPS * BB * EP;
  const size_t stride = (size_t)gridDim.x * blockDim.x;
  for (size_t i = (size_t)blockIdx.x * blockDim.x + threadIdx.x; i < N; i += stride) {
    int e = (int)(i % EP);
    size_t tb = i / EP;
    float v = 0.f;
    if (e < EE) v = emb[(size_t)texts[tb] * EE + e];
    x0[i] = (_Float16)v;
  }
}

__global__ void prep_b(const float* __restrict__ bih0, const float* __restrict__ bhh0,
                       const float* __restrict__ bih1, const float* __restrict__ bhh1,
                       float* __restrict__ bias0, float* __restrict__ bias1) {
  int i = blockIdx.x * blockDim.x + threadIdx.x;
  if (i < HH) {
    bias0[i]        = bih0[i] + bhh0[i];
    bias0[512 + i]  = bih0[512 + i] + bhh0[512 + i];
    bias0[1024 + i] = bih0[1024 + i];
    bias0[1536 + i] = bhh0[1024 + i];
    bias1[i]        = bih1[i] + bhh1[i];
    bias1[512 + i]  = bih1[512 + i] + bhh1[512 + i];
    bias1[1024 + i] = bih1[1024 + i];
    bias1[1536 + i] = bhh1[1024 + i];
  }
}

// 128 WGs x 256 threads. WG 0..63 = layer0 (8-col slices), 64..127 = layer1.
// Weights LDS-resident (round-11 win). Round-13: ONE detect barrier per stage
// per layer (concurrent wave-0/wave-1 polls), all movable work (x-MFMA,
// prefetches, pooled) in the post-publish tail, sleep-backoff polls.
__global__ __launch_bounds__(256, 1) void gru_persistent(
    const _Float16* __restrict__ x0,
    const float* __restrict__ Wih0, const float* __restrict__ Whh0,
    const float* __restrict__ Wih1, const float* __restrict__ Whh1,
    const float* __restrict__ bias0, const float* __restrict__ bias1,
    _Float16* h1ring, _Float16* h2buf, float* pooled,
    int* flags0, int* flags1)
{
  const int wg   = blockIdx.x;
  const int L    = wg >> 6;
  const int w    = wg & 63;
  const int jb   = w * NCOL;
  const int tid  = threadIdx.x;
  const int bsub = tid >> 6;          // wave index: owns batch rows 16*bsub..+15
  const int lane = tid & 63;
  const int quad = lane >> 4;
  const int l15  = lane & 15;
  const int jj   = l15 & 7;           // real column within slice (lanes 8-15 dup)
  const int brow = bsub * 16 + l15;   // A-operand row (batch)
  const int j    = jb + jj;           // output column (for bias)
  const int kq   = quad * 8;
  const int hoff = brow * (HH * 2) + quad * 16;   // byte voffset into an h slot

  __shared__ _Float16 wlds[24576];          // 49152 B: 32 chunks x 768 halves
  __shared__ _Float16 tile[2][4][16][NCOL]; // 2048 B, wave-private b x j tiles

  // ---- one-time LDS weight fill from fp32 globals ----
  if (L == 0) {
    // chunks 0..9 = W0x (K=320, cols >=300 zero), 10..25 = W0h (K=512)
    for (int idx = tid; idx < 26 * 96; idx += 256) {
      int q = idx & 3, j8 = (idx >> 2) & 7, g = (idx >> 5) % 3, ch = idx / 96;
      int row = g * 512 + jb + j8;
      _Float16* dst = wlds + ch * 768 + g * 256 + j8 * 32 + q * 8;
      if (ch < 10) {
        int colb = ch * 32 + q * 8;
        #pragma unroll
        for (int e = 0; e < 8; ++e) {
          int col = colb + e;
          dst[e] = (col < EE) ? (_Float16)Wih0[(size_t)row * EE + col] : (_Float16)0.f;
        }
      } else {
        int colb = (ch - 10) * 32 + q * 8;
        #pragma unroll
        for (int e = 0; e < 8; ++e)
          dst[e] = (_Float16)Whh0[(size_t)row * HH + colb + e];
      }
    }
  } else {
    // chunks 0..15 = W1x, 16..31 = W1h (both K=512)
    for (int idx = tid; idx < 32 * 96; idx += 256) {
      int q = idx & 3, j8 = (idx >> 2) & 7, g = (idx >> 5) % 3, ch = idx / 96;
      int row = g * 512 + jb + j8;
      const float* src = (ch < 16) ? Wih1 : Whh1;
      int colb = ((ch < 16) ? ch : ch - 16) * 32 + q * 8;
      _Float16* dst = wlds + ch * 768 + g * 256 + j8 * 32 + q * 8;
      #pragma unroll
      for (int e = 0; e < 8; ++e)
        dst[e] = (_Float16)src[(size_t)row * HH + colb + e];
    }
  }
  __syncthreads();

  if (L == 0) {
    const float br = bias0[j], bz = bias0[512 + j];
    const float bnx = bias0[1024 + j], bnh = bias0[1536 + j];
    const int xoff = brow * (EP * 2) + quad * 16;
    // preloop: x-part for s=0 (off critical path)
    f32x4 xR = {0.f,0.f,0.f,0.f}, xZ = {0.f,0.f,0.f,0.f}, xN = {0.f,0.f,0.f,0.f};
    {
      i32x4 xq[10];
      loadx10_wait(xq, x0, xoff);
      #pragma unroll 5
      for (int c = 0; c < 10; ++c) {
        f16x8 a = fragq(xq[c]);
        B3 bb = ldsB(wlds, c, jj, kq);
        xR = mf(a, bb.r, xR); xZ = mf(a, bb.z, xZ); xN = mf(a, bb.n, xN);
      }
    }
    for (int s = 0; s < T_STEPS; ++s) {
      // ONE detect barrier: wave0 = own-layer all-to-all, wave1 = ring throttle
      wg_waitv((s >= 1)    ? flags0 : nullptr, s,
               (s >= RING) ? flags1 : nullptr, s - RING + 1);
      f32x4 hR = {0.f,0.f,0.f,0.f}, hZ = {0.f,0.f,0.f,0.f}, hN = {0.f,0.f,0.f,0.f};
      if (s >= 1) {
        HMat hA;
        load16_mall(hA, h1ring + ((s - 1) & (RING - 1)) * HB, hoff);
        #pragma unroll 4
        for (int c = 0; c < 16; ++c) {
          f16x8 a = fragq(hA.q[c]);
          B3 bb = ldsB(wlds, 10 + c, jj, kq);
          hR = mf(a, bb.r, hR); hZ = mf(a, bb.z, hZ); hN = mf(a, bb.n, hN);
        }
      }

      _Float16 (*tc)[NCOL] = tile[s & 1][bsub];
      _Float16 (*tp)[NCOL] = tile[(s + 1) & 1][bsub];
      #pragma unroll
      for (int rg = 0; rg < 4; ++rg) {
        const int rr = quad * 4 + rg;           // C/D row = quad*4+reg
        float r = sigf(xR[rg] + hR[rg] + br);
        float z = sigf(xZ[rg] + hZ[rg] + bz);
        float n = tanhf(xN[rg] + bnx + r * (hN[rg] + bnh));
        float hp = (s >= 1) ? (float)tp[rr][jj] : 0.f;
        if (l15 < 8) tc[rr][l15] = (_Float16)((1.f - z) * n + z * hp);
      }
      if (lane < 16) {                          // publish own 16 rows (16B each)
        f16x8 v = *(const f16x8*)&tc[lane][0];
        st16_mall(h1ring + (s & (RING - 1)) * HB + (size_t)(bsub * 16 + lane) * HH + jb, v);
      }
      __builtin_amdgcn_s_waitcnt(0);            // own h stores at MALL
      __syncthreads();                          // all 4 waves drained
      if (tid == 0) st4_dev(flags0 + w * 16, s + 1);   // one word, own line
      // TAIL (off critical path): x-prefetch + x-MFMA for s+1
      if (s + 1 < T_STEPS) {
        i32x4 xq[10];
        loadx10_wait(xq, x0 + (size_t)(s + 1) * BB * EP, xoff);
        xR = (f32x4){0.f,0.f,0.f,0.f}; xZ = (f32x4){0.f,0.f,0.f,0.f};
        xN = (f32x4){0.f,0.f,0.f,0.f};
        #pragma unroll 5
        for (int c = 0; c < 10; ++c) {
          f16x8 a = fragq(xq[c]);
          B3 bb = ldsB(wlds, c, jj, kq);
          xR = mf(a, bb.r, xR); xZ = mf(a, bb.z, xZ); xN = mf(a, bb.n, xN);
        }
      }
    }
  } else {
    const float br = bias1[j], bz = bias1[512 + j];
    const float bnx = bias1[1024 + j], bnh = bias1[1536 + j];
    // preloop: prefetch h1[0] and its x-part accumulators (off critical path)
    f32x4 xR = {0.f,0.f,0.f,0.f}, xZ = {0.f,0.f,0.f,0.f}, xN = {0.f,0.f,0.f,0.f};
    {
      wg_waitv(flags0, 1, nullptr, 0);
      HMat A1;
      load16_mall(A1, h1ring, hoff);
      #pragma unroll 4
      for (int c = 0; c < 16; ++c) {
        f16x8 a = fragq(A1.q[c]);
        B3 bb = ldsB(wlds, c, jj, kq);
        xR = mf(a, bb.r, xR); xZ = mf(a, bb.z, xZ); xN = mf(a, bb.n, xN);
      }
    }
    for (int t = 0; t < T_STEPS; ++t) {
      // ONE fused detect: wave0 = self-recurrence (critical), wave1 = L0 lead
      wg_waitv((t >= 1) ? flags1 : nullptr, t,
               (t + 1 < T_STEPS) ? flags0 : nullptr, t + 2);
      f32x4 hR = {0.f,0.f,0.f,0.f}, hZ = {0.f,0.f,0.f,0.f}, hN = {0.f,0.f,0.f,0.f};
      if (t >= 1) {
        HMat A2;
        load16_mall(A2, h2buf + ((t - 1) & 1) * HB, hoff);
        #pragma unroll 4
        for (int c = 0; c < 16; ++c) {
          f16x8 a = fragq(A2.q[c]);
          B3 bb = ldsB(wlds, 16 + c, jj, kq);
          hR = mf(a, bb.r, hR); hZ = mf(a, bb.z, hZ); hN = mf(a, bb.n, hN);
        }
      }

      _Float16 (*tc)[NCOL] = tile[t & 1][bsub];
      _Float16 (*tp)[NCOL] = tile[(t + 1) & 1][bsub];
      #pragma unroll
      for (int rg = 0; rg < 4; ++rg) {
        const int rr = quad * 4 + rg;
        float r = sigf(xR[rg] + hR[rg] + br);
        float z = sigf(xZ[rg] + hZ[rg] + bz);
        float n = tanhf(xN[rg] + bnx + r * (hN[rg] + bnh));
        float hp = (t >= 1) ? (float)tp[rr][jj] : 0.f;
        if (l15 < 8) tc[rr][l15] = (_Float16)((1.f - z) * n + z * hp);
      }
      if (lane < 16) {
        f16x8 v = *(const f16x8*)&tc[lane][0];
        st16_mall(h2buf + (t & 1) * HB + (size_t)(bsub * 16 + lane) * HH + jb, v);
      }
      __builtin_amdgcn_s_waitcnt(0);
      __syncthreads();
      if (tid == 0) st4_dev(flags1 + w * 16, t + 1);

      // TAIL (off critical path): pooled partial, A1[t+1] load + x-part MFMAs
      if (lane < 8) {
        float sum = 0.f;
        #pragma unroll
        for (int r = 0; r < 16; ++r) sum += (float)tc[r][lane];
        atomicAdd(pooled + (size_t)t * HH + jb + lane, sum);   // raw sum; /64 in FC
      }
      if (t + 1 < T_STEPS) {
        HMat A1;
        load16_mall(A1, h1ring + ((t + 1) & (RING - 1)) * HB, hoff);
        xR = (f32x4){0.f,0.f,0.f,0.f}; xZ = (f32x4){0.f,0.f,0.f,0.f};
        xN = (f32x4){0.f,0.f,0.f,0.f};
        #pragma unroll 4
        for (int c = 0; c < 16; ++c) {
          f16x8 a = fragq(A1.q[c]);
          B3 bb = ldsB(wlds, c, jj, kq);
          xR = mf(a, bb.r, xR); xZ = mf(a, bb.z, xZ); xN = mf(a, bb.n, xN);
        }
      }
    }
  }
}

__global__ void fc_kernel(const float* __restrict__ pooled, const float* __restrict__ fcW,
                          const float* __restrict__ fcb, float* __restrict__ out) {
  const int t = blockIdx.x;
  const int lane = threadIdx.x;  // 64 = one wave
  float a0 = 0.f, a1 = 0.f, a2 = 0.f, a3 = 0.f, a4 = 0.f;
  for (int jj = lane; jj < HH; jj += 64) {
    float p = pooled[(size_t)t * HH + jj];
    a0 += p * fcW[jj];
    a1 += p * fcW[512 + jj];
    a2 += p * fcW[1024 + jj];
    a3 += p * fcW[1536 + jj];
    a4 += p * fcW[2048 + jj];
  }
  #pragma unroll
  for (int off = 32; off > 0; off >>= 1) {
    a0 += __shfl_down(a0, off, 64);
    a1 += __shfl_down(a1, off, 64);
    a2 += __shfl_down(a2, off, 64);
    a3 += __shfl_down(a3, off, 64);
    a4 += __shfl_down(a4, off, 64);
  }
  if (lane == 0) {
    const float sc = 1.f / 64.f;
    out[t * 5 + 0] = a0 * sc + fcb[0];
    out[t * 5 + 1] = a1 * sc + fcb[1];
    out[t * 5 + 2] = a2 * sc + fcb[2];
    out[t * 5 + 3] = a3 * sc + fcb[3];
    out[t * 5 + 4] = a4 * sc + fcb[4];
  }
}

extern "C" void kernel_launch(void* const* d_in, const int* in_sizes, int n_in,
                              void* d_out, int out_size, void* d_ws, size_t ws_size,
                              hipStream_t stream) {
  const int*   texts = (const int*)  d_in[0];
  const float* emb   = (const float*)d_in[1];
  const float* Wih0  = (const float*)d_in[2];
  const float* Whh0  = (const float*)d_in[3];
  const float* bih0  = (const float*)d_in[4];
  const float* bhh0  = (const float*)d_in[5];
  const float* Wih1  = (const float*)d_in[6];
  const float* Whh1  = (const float*)d_in[7];
  const float* bih1  = (const float*)d_in[8];
  const float* bhh1  = (const float*)d_in[9];
  const float* fcW   = (const float*)d_in[10];
  const float* fcb   = (const float*)d_in[11];
  float* out = (float*)d_out;

  char* ws = (char*)d_ws;
  int*      flags0 = (int*)ws;                        // 4096 B: 64 words, 64B apart
  int*      flags1 = (int*)(ws + 4096);               // 4096 B
  float*    pooled = (float*)(ws + 8192);             // 1048576 B [512][512] f32
  _Float16* h1ring = (_Float16*)(ws + 1056768);       // 524288 B (8 x 64x512 f16)
  _Float16* h2buf  = (_Float16*)(ws + 1581056);       // 131072 B (2 slots)
  _Float16* x0     = (_Float16*)(ws + 1712128);       // 20971520 B [512][64][320]
  float*    bias0  = (float*)(ws + 22683648);         // 8192 B (r,z,nx,nh)
  float*    bias1  = (float*)(ws + 22691840);         // 8192 B
  // total ws use: 22700032 B

  hipMemsetAsync(ws, 0, 1056768, stream);  // flags0 + flags1 + pooled = zeros
  prep_x0<<<4096, 256, 0, stream>>>(texts, emb, x0);
  prep_b<<<2, 256, 0, stream>>>(bih0, bhh0, bih1, bhh1, bias0, bias1);
  gru_persistent<<<128, 256, 0, stream>>>(x0, Wih0, Whh0, Wih1, Whh1, bias0, bias1,
                                          h1ring, h2buf, pooled, flags0, flags1);
  fc_kernel<<<512, 64, 0, stream>>>(pooled, fcW, fcb, out);
}